// Round 1
// baseline (11295.390 us; speedup 1.0000x reference)
//
#include <hip/hip_runtime.h>

// PositionCloser round 14: move the h@W_hh matvec off the VALU onto the idle
// MFMA pipe. Evidence: MfmaUtil=0, VALUBusy=87.6%, and VGPR_Count=116 < the
// 128 weight dwords -> R13's asm-"v" trick still left weights AGPR-parked
// with per-use v_accvgpr_read copies (explains ~2x busy-cycle vs source
// instruction count). Fix: weights become MFMA B-operands (AGPR residency is
// then FREE - MFMA reads AGPRs directly). Trick: every lane-group loads the
// SAME h as its A k-chunk -> all 16 A-rows equal h -> all D rows identical ->
// acc[0] at lane l = preact[16t + (l&15)] for every lane. B packed with
// n = 16t+col, so lane l gets all 4 gates of hid=lane from tiles {u,4+u,8+u,
// 12+u}, u=l>>4, via 12 cndmasks. A-frag read straight from the f16 h-row in
// the LDS ring (2 broadcast ds_read_b128; same-wave DS ops are in-order).
// Shell (ring, flags, loss wave) identical to R13.

#define CH  128
#define HID 64

typedef __fp16 half8 __attribute__((ext_vector_type(8)));
typedef float  f32x4 __attribute__((ext_vector_type(4)));

__device__ __forceinline__ float rlf(float v, int l) {
  return __builtin_bit_cast(float, __builtin_amdgcn_readlane(__builtin_bit_cast(int, v), l));
}
__device__ __forceinline__ float frcp(float x) { return __builtin_amdgcn_rcpf(x); }
__device__ __forceinline__ float sigm(float x) { return frcp(1.0f + __expf(-x)); }
__device__ __forceinline__ float tanh_(float x) {
  float e = __expf(2.0f * x);
  return 1.0f - 2.0f * frcp(e + 1.0f);
}
template <int CTRL, int RMASK>
__device__ __forceinline__ float dpp_add(float v) {
  int x = __builtin_amdgcn_update_dpp(0, __builtin_bit_cast(int, v), CTRL, RMASK, 0xF, true);
  return v + __builtin_bit_cast(float, x);
}
__device__ __forceinline__ float dpp_wave_sum(float v) {  // total lands in lane 63
  v = dpp_add<0x111, 0xF>(v);
  v = dpp_add<0x112, 0xF>(v);
  v = dpp_add<0x114, 0xF>(v);
  v = dpp_add<0x118, 0xF>(v);
  v = dpp_add<0x142, 0xA>(v);   // row_bcast:15
  v = dpp_add<0x143, 0xC>(v);   // row_bcast:31
  return v;
}

__global__ __attribute__((amdgpu_flat_work_group_size(128, 128), amdgpu_waves_per_eu(2, 2)))
void pc_lstm_kernel(const int* __restrict__ inds,
                    const float* __restrict__ p,
                    const float* __restrict__ ls_probs,
                    const float* __restrict__ open_probs,
                    const int* __restrict__ open_slices,
                    const float* __restrict__ open_hx,
                    const float* __restrict__ W_ih,
                    const float* __restrict__ W_hh,
                    const float* __restrict__ b_ih,
                    const float* __restrict__ b_hh,
                    const float* __restrict__ W_out,
                    const float* __restrict__ b_out,
                    const int* __restrict__ n_chunks_p,
                    float* __restrict__ out)
{
  __shared__ __fp16 ring[2][CH][HID];   // 32 KB: h history for the lagged loss
  __shared__ int prod;                  // chunks fully written by wave0
  __shared__ int cons;                  // chunks fully consumed by wave1

  const int tid  = threadIdx.x;
  const int wv   = tid >> 6;           // 0 = compute, 1 = loss
  const int lane = tid & 63;
  const int s    = blockIdx.x;         // one sequence per block
  const int n_chunks = n_chunks_p[0];
  const int tbase = inds[s >> 4] + (s & 15);
  const float2* p2 = (const float2*)p;

  if (tid == 0) { prod = 0; cons = 0; }
  __syncthreads();                      // only barrier in the kernel

  if (wv == 0) {
    // ================= compute wave =================
    const int kg = lane >> 4;          // k-group (A/B fragment k-chunk index)
    const int cc = lane & 15;          // column within a 16-wide N-tile

    // B fragments: tile t covers preact rows n = 16t + col; k = 32*kc + 8*kg + j.
    // Any consistent k-permutation between A and B packing is valid (dot sums
    // over k symmetrically), so only the lane structure (col=l&15, k-grp=l>>4)
    // must match hardware.
    half8 Wb[32];
#pragma unroll
    for (int t = 0; t < 16; ++t) {
#pragma unroll
      for (int kc = 0; kc < 2; ++kc) {
        const float* wp = W_hh + (16 * t + cc) * HID + 32 * kc + 8 * kg;
        half8 w;
#pragma unroll
        for (int j = 0; j < 8; ++j) w[j] = (__fp16)wp[j];
        Wb[2 * t + kc] = w;
      }
    }

    float wxa[4], wxb[4], bb[4];
#pragma unroll
    for (int g = 0; g < 4; ++g) {
      const int r = g * HID + lane;
      wxa[g] = W_ih[2 * r];
      wxb[g] = W_ih[2 * r + 1];
      bb[g]  = b_ih[r] + b_hh[r];
    }
    float h = open_hx[(s * 2 + 0) * HID + lane];
    float c = open_hx[(s * 2 + 1) * HID + lane];

    // Seed the A-source row: arow always points at the f16 image of current h.
    ring[1][CH - 1][lane] = (__fp16)h;
    const __fp16* arow = &ring[1][CH - 1][0];

    const bool u1 = (lane & 16) != 0;  // bit0 of u = lane>>4
    const bool u2 = (lane & 32) != 0;  // bit1 of u
    const f32x4 zero4 = {0.f, 0.f, 0.f, 0.f};

    float2 curA = p2[tbase + lane];
    float2 curB = p2[tbase + HID + lane];
    float2 nxtA = curA, nxtB = curB;

    for (int off = 0; off < n_chunks; ++off) {
      if (off) { curA = nxtA; curB = nxtB; }
      const float px0 = rlf(curA.x, 0);
      const float px1 = rlf(curA.y, 0);
      float2 xA, xB;                       // pre-subtracted chunk base
      xA.x = curA.x - px0; xA.y = curA.y - px1;
      xB.x = curB.x - px0; xB.y = curB.y - px1;
      if (off + 1 < n_chunks) {
        const int nb = tbase + (off + 1) * CH;
        nxtA = p2[nb + lane];
        nxtB = p2[nb + HID + lane];
      }
      while (__hip_atomic_load(&cons, __ATOMIC_ACQUIRE, __HIP_MEMORY_SCOPE_WORKGROUP) + 2 <= off)
        __builtin_amdgcn_s_sleep(8);

      __fp16* slot = &ring[off & 1][0][0];
#pragma unroll
      for (int hf = 0; hf < 2; ++hf) {
        const float xcx = hf ? xB.x : xA.x;
        const float xcy = hf ? xB.y : xA.y;
#pragma unroll 1
        for (int tl = 0; tl < 64; ++tl) {
          // A fragments: lane-group kg reads h[8*kg .. 8*kg+7] (+32 for frag1).
          // 4 distinct 16B addresses -> pure broadcast, conflict-free.
          const char* ab = (const char*)arow + 16 * kg;
          const half8 a0 = *(const half8*)(ab);        // k = 0..31
          const half8 a1 = *(const half8*)(ab + 64);   // k = 32..63

          const float x0 = rlf(xcx, tl);
          const float x1 = rlf(xcy, tl);

          // All A-rows equal h  ->  every lane's acc[0] = preact[16t + (l&15)].
          float pre[16];
#pragma unroll
          for (int t = 0; t < 16; ++t) {
            f32x4 acc = __builtin_amdgcn_mfma_f32_16x16x32_f16(a0, Wb[2 * t],     zero4, 0, 0, 0);
            acc       = __builtin_amdgcn_mfma_f32_16x16x32_f16(a1, Wb[2 * t + 1], acc,   0, 0, 0);
            pre[t] = acc[0];
          }

          // Gate g of hid=lane lives in tile 4g + u  (u = lane>>4).
          float pa[4];
#pragma unroll
          for (int g = 0; g < 4; ++g) {
            const float s01 = u1 ? pre[4 * g + 1] : pre[4 * g + 0];
            const float s23 = u1 ? pre[4 * g + 3] : pre[4 * g + 2];
            const float dg  = u2 ? s23 : s01;
            pa[g] = fmaf(x0, wxa[g], fmaf(x1, wxb[g], dg + bb[g]));
          }

          const float ig = sigm(pa[0]);
          const float fg = sigm(pa[1]);
          const float gg = tanh_(pa[2]);
          const float og = sigm(pa[3]);
          c = fmaf(fg, c, ig * gg);
          h = og * tanh_(c);

          const int tt = hf * 64 + tl;
          slot[tt * HID + lane] = (__fp16)h;   // ds_write_b16 (ring + next A-src)
          arow = &slot[tt * HID];              // next step reads the row just written
        }
      }
      if (lane == 0)
        __hip_atomic_store(&prod, off + 1, __ATOMIC_RELEASE, __HIP_MEMORY_SCOPE_WORKGROUP);
    }
  } else {
    // ================= loss wave =================
    const float wo   = W_out[lane];
    const float bout = b_out[0];
    const int   os   = open_slices[s];
    const float OL   = __logf(p[2 * os]) + __logf(p[2 * os + 1]);
    const float coef = open_probs[s] * (2.0f * ls_probs[s] - 1.0f);

    float S = 1.0f, D = 1.0f, lsum = 0.0f, psum = 0.0f;

    for (int off = 0; off < n_chunks; ++off) {
      const int cb = tbase + off * CH;
      const float2 cA = p2[cb + lane];
      const float2 cB = p2[cb + HID + lane];
      const float LA = __logf(cA.x) + __logf(cA.y);
      const float LB = __logf(cB.x) + __logf(cB.y);

      while (__hip_atomic_load(&prod, __ATOMIC_ACQUIRE, __HIP_MEMORY_SCOPE_WORKGROUP) <= off)
        __builtin_amdgcn_s_sleep(32);

      const __fp16* slot = &ring[off & 1][0][0];
#pragma unroll 1
      for (int tt = 0; tt < CH; ++tt) {
        const float hv = (float)slot[tt * HID + lane];
        const float z  = rlf(dpp_wave_sum(hv * wo), 63);
        const float pr = sigm(z + bout);
        const float Lt = (tt < 64) ? rlf(LA, tt) : rlf(LB, tt - 64);
        const float pn = (tt == 0) ? pr : pr * D;
        lsum = fmaf(pn, Lt, lsum);
        psum += pn;
        if (tt == 0)           D = S * (1.0f - pr);   // chunk t=0 undiscounted (ref quirk)
        else if (tt < CH - 1)  D *= (1.0f - pr);
        else                   S = D;                  // carry excludes (1-p_last)
      }
      if (lane == 0)
        __hip_atomic_store(&cons, off + 1, __ATOMIC_RELEASE, __HIP_MEMORY_SCOPE_WORKGROUP);
    }
    if (lane == 0) atomicAdd(out, coef * (lsum - OL * psum));
  }
}

extern "C" void kernel_launch(void* const* d_in, const int* in_sizes, int n_in,
                              void* d_out, int out_size, void* d_ws, size_t ws_size,
                              hipStream_t stream) {
  (void)hipMemsetAsync(d_out, 0, sizeof(float), stream);

  pc_lstm_kernel<<<dim3(1024), dim3(128), 0, stream>>>(
      (const int*)d_in[0],    // inds
      (const float*)d_in[1],  // p
      (const float*)d_in[2],  // ls_probs
      (const float*)d_in[3],  // open_probs
      (const int*)d_in[4],    // open_slices
      (const float*)d_in[5],  // open_hx
      (const float*)d_in[6],  // W_ih
      (const float*)d_in[7],  // W_hh
      (const float*)d_in[8],  // b_ih
      (const float*)d_in[9],  // b_hh
      (const float*)d_in[10], // W_out
      (const float*)d_in[11], // b_out
      (const int*)d_in[12],   // n_chunks
      (float*)d_out);
}

// Round 2
// 7031.901 us; speedup vs baseline: 1.6063x; 1.6063x over previous
//
#include <hip/hip_runtime.h>

// PositionCloser round 15: R14 (MFMA matvec) minus its two pathologies.
// Evidence from R14: WRITE_SIZE 32->4128 KB (prologue scratch spill: Wb 128
// + 64 live accs + state > 256-reg cap) and 1654 cyc/step vs 540 VALU-busy +
// 490 MFMA-busy -> phases serialize behind a ds_write->ds_read LDS round
// trip at the head of every step (generic-pointer A reads, pure latency,
// 1 compute wave/SIMD = nothing hides it).
// Fix 1: build MFMA A-fragments with 8 ds_bpermute_b32 from the packed-f16
// h pairs (static lane permutation, no LDS round trip; ring write stays for
// the loss wave but leaves the critical path).
// Fix 2: process tiles per gate-group (4 tiles -> cndmask select -> pa[g]):
// peak acc liveness 64->16 regs, VALU selects co-issue under the MFMA burst,
// total pressure ~200 regs < 256 cap -> no spill.
// Mapping identical to R14 (HW-verified, absmax 0.0): all 16 A-rows equal h
// -> acc[0] at lane l = preact[16t + (l&15)]; gate g of hid=lane in tile
// 4g + (lane>>4). Shell (ring, flags, loss wave) identical to R13/R14.

#define CH  128
#define HID 64

typedef __fp16 half8 __attribute__((ext_vector_type(8)));
typedef float  f32x4 __attribute__((ext_vector_type(4)));
typedef int    int4v __attribute__((ext_vector_type(4)));

__device__ __forceinline__ float rlf(float v, int l) {
  return __builtin_bit_cast(float, __builtin_amdgcn_readlane(__builtin_bit_cast(int, v), l));
}
__device__ __forceinline__ int packh(float a, float b) {
  return __builtin_bit_cast(int, __builtin_amdgcn_cvt_pkrtz(a, b));
}
__device__ __forceinline__ float frcp(float x) { return __builtin_amdgcn_rcpf(x); }
__device__ __forceinline__ float sigm(float x) { return frcp(1.0f + __expf(-x)); }
__device__ __forceinline__ float tanh_(float x) {
  float e = __expf(2.0f * x);
  return 1.0f - 2.0f * frcp(e + 1.0f);
}
template <int CTRL, int RMASK>
__device__ __forceinline__ float dpp_add(float v) {
  int x = __builtin_amdgcn_update_dpp(0, __builtin_bit_cast(int, v), CTRL, RMASK, 0xF, true);
  return v + __builtin_bit_cast(float, x);
}
__device__ __forceinline__ float dpp_xor1(float v) {  // quad_perm [1,0,3,2]
  int x = __builtin_amdgcn_update_dpp(0, __builtin_bit_cast(int, v), 0xB1, 0xF, 0xF, true);
  return __builtin_bit_cast(float, x);
}
__device__ __forceinline__ float dpp_wave_sum(float v) {  // total lands in lane 63
  v = dpp_add<0x111, 0xF>(v);
  v = dpp_add<0x112, 0xF>(v);
  v = dpp_add<0x114, 0xF>(v);
  v = dpp_add<0x118, 0xF>(v);
  v = dpp_add<0x142, 0xA>(v);   // row_bcast:15
  v = dpp_add<0x143, 0xC>(v);   // row_bcast:31
  return v;
}

__global__ __attribute__((amdgpu_flat_work_group_size(128, 128), amdgpu_waves_per_eu(2, 2)))
void pc_lstm_kernel(const int* __restrict__ inds,
                    const float* __restrict__ p,
                    const float* __restrict__ ls_probs,
                    const float* __restrict__ open_probs,
                    const int* __restrict__ open_slices,
                    const float* __restrict__ open_hx,
                    const float* __restrict__ W_ih,
                    const float* __restrict__ W_hh,
                    const float* __restrict__ b_ih,
                    const float* __restrict__ b_hh,
                    const float* __restrict__ W_out,
                    const float* __restrict__ b_out,
                    const int* __restrict__ n_chunks_p,
                    float* __restrict__ out)
{
  __shared__ __fp16 ring[2][CH][HID];   // 32 KB: h history for the lagged loss
  __shared__ int prod;                  // chunks fully written by wave0
  __shared__ int cons;                  // chunks fully consumed by wave1

  const int tid  = threadIdx.x;
  const int wv   = tid >> 6;           // 0 = compute, 1 = loss
  const int lane = tid & 63;
  const int s    = blockIdx.x;         // one sequence per block
  const int n_chunks = n_chunks_p[0];
  const int tbase = inds[s >> 4] + (s & 15);
  const float2* p2 = (const float2*)p;

  if (tid == 0) { prod = 0; cons = 0; }
  __syncthreads();                      // only barrier in the kernel

  if (wv == 0) {
    // ================= compute wave =================
    const int kg = lane >> 4;          // k-group (A/B fragment k-chunk index)
    const int cc = lane & 15;          // column within a 16-wide N-tile

    // B fragments (same HW-verified packing as R14): tile t covers preact
    // rows n = 16t + col; k = 32*kc + 8*kg + j.
    half8 Wb[32];
#pragma unroll
    for (int t = 0; t < 16; ++t) {
#pragma unroll
      for (int kc = 0; kc < 2; ++kc) {
        const float* wp = W_hh + (16 * t + cc) * HID + 32 * kc + 8 * kg;
        half8 w;
#pragma unroll
        for (int j = 0; j < 8; ++j) w[j] = (__fp16)wp[j];
        Wb[2 * t + kc] = w;
      }
    }

    float wxa[4], wxb[4], bb[4];
#pragma unroll
    for (int g = 0; g < 4; ++g) {
      const int r = g * HID + lane;
      wxa[g] = W_ih[2 * r];
      wxb[g] = W_ih[2 * r + 1];
      bb[g]  = b_ih[r] + b_hh[r];
    }
    float h = open_hx[(s * 2 + 0) * HID + lane];
    float c = open_hx[(s * 2 + 1) * HID + lane];

    // bpermute byte-indices for the A fragments (loop-invariant):
    // a0 word w pulls hp from lane 8*kg+2w;  a1 word w from lane 32+8*kg+2w.
    int ia0[4], ia1[4];
#pragma unroll
    for (int w = 0; w < 4; ++w) {
      ia0[w] = 4 * (8 * kg + 2 * w);
      ia1[w] = 4 * (32 + 8 * kg + 2 * w);
    }

    const bool u1 = (lane & 16) != 0;  // bit0 of u = lane>>4
    const bool u2 = (lane & 32) != 0;  // bit1 of u
    const f32x4 zero4 = {0.f, 0.f, 0.f, 0.f};

    float2 curA = p2[tbase + lane];
    float2 curB = p2[tbase + HID + lane];
    float2 nxtA = curA, nxtB = curB;

    for (int off = 0; off < n_chunks; ++off) {
      if (off) { curA = nxtA; curB = nxtB; }
      const float px0 = rlf(curA.x, 0);
      const float px1 = rlf(curA.y, 0);
      float2 xA, xB;                       // pre-subtracted chunk base
      xA.x = curA.x - px0; xA.y = curA.y - px1;
      xB.x = curB.x - px0; xB.y = curB.y - px1;
      if (off + 1 < n_chunks) {
        const int nb = tbase + (off + 1) * CH;
        nxtA = p2[nb + lane];
        nxtB = p2[nb + HID + lane];
      }
      while (__hip_atomic_load(&cons, __ATOMIC_ACQUIRE, __HIP_MEMORY_SCOPE_WORKGROUP) + 2 <= off)
        __builtin_amdgcn_s_sleep(8);

      __fp16* slot = &ring[off & 1][0][0];
#pragma unroll
      for (int hf = 0; hf < 2; ++hf) {
        const float xcx = hf ? xB.x : xA.x;
        const float xcy = hf ? xB.y : xA.y;
#pragma unroll 1
        for (int tl = 0; tl < 64; ++tl) {
          // ---- A fragments via crossbar (no LDS round trip) ----
          const int hp = packh(h, dpp_xor1(h));   // even lane 2j: (h_2j, h_2j+1)
          int4v A0, A1;
#pragma unroll
          for (int w = 0; w < 4; ++w) {
            A0[w] = __builtin_amdgcn_ds_bpermute(ia0[w], hp);
            A1[w] = __builtin_amdgcn_ds_bpermute(ia1[w], hp);
          }
          const half8 a0 = __builtin_bit_cast(half8, A0);   // k = 0..31 slice
          const half8 a1 = __builtin_bit_cast(half8, A1);   // k = 32..63 slice

          const float x0 = rlf(xcx, tl);
          const float x1 = rlf(xcy, tl);

          // ---- per-gate MFMA group: 4 tiles -> select -> preactivation ----
          // caps acc liveness at 16 regs; selects/bias co-issue under MFMA
          float pa[4];
#pragma unroll
          for (int g = 0; g < 4; ++g) {
            f32x4 q0 = __builtin_amdgcn_mfma_f32_16x16x32_f16(a0, Wb[8 * g + 0], zero4, 0, 0, 0);
            q0       = __builtin_amdgcn_mfma_f32_16x16x32_f16(a1, Wb[8 * g + 1], q0,    0, 0, 0);
            f32x4 q1 = __builtin_amdgcn_mfma_f32_16x16x32_f16(a0, Wb[8 * g + 2], zero4, 0, 0, 0);
            q1       = __builtin_amdgcn_mfma_f32_16x16x32_f16(a1, Wb[8 * g + 3], q1,    0, 0, 0);
            f32x4 q2 = __builtin_amdgcn_mfma_f32_16x16x32_f16(a0, Wb[8 * g + 4], zero4, 0, 0, 0);
            q2       = __builtin_amdgcn_mfma_f32_16x16x32_f16(a1, Wb[8 * g + 5], q2,    0, 0, 0);
            f32x4 q3 = __builtin_amdgcn_mfma_f32_16x16x32_f16(a0, Wb[8 * g + 6], zero4, 0, 0, 0);
            q3       = __builtin_amdgcn_mfma_f32_16x16x32_f16(a1, Wb[8 * g + 7], q3,    0, 0, 0);
            const float s01 = u1 ? q1[0] : q0[0];
            const float s23 = u1 ? q3[0] : q2[0];
            const float dg  = u2 ? s23 : s01;
            pa[g] = fmaf(x0, wxa[g], fmaf(x1, wxb[g], dg + bb[g]));
          }

          const float ig = sigm(pa[0]);
          const float fg = sigm(pa[1]);
          const float gg = tanh_(pa[2]);
          const float og = sigm(pa[3]);
          c = fmaf(fg, c, ig * gg);
          h = og * tanh_(c);

          const int tt = hf * 64 + tl;
          slot[tt * HID + lane] = (__fp16)h;   // ds_write_b16 (ring, off chain)
        }
      }
      if (lane == 0)
        __hip_atomic_store(&prod, off + 1, __ATOMIC_RELEASE, __HIP_MEMORY_SCOPE_WORKGROUP);
    }
  } else {
    // ================= loss wave =================
    const float wo   = W_out[lane];
    const float bout = b_out[0];
    const int   os   = open_slices[s];
    const float OL   = __logf(p[2 * os]) + __logf(p[2 * os + 1]);
    const float coef = open_probs[s] * (2.0f * ls_probs[s] - 1.0f);

    float S = 1.0f, D = 1.0f, lsum = 0.0f, psum = 0.0f;

    for (int off = 0; off < n_chunks; ++off) {
      const int cb = tbase + off * CH;
      const float2 cA = p2[cb + lane];
      const float2 cB = p2[cb + HID + lane];
      const float LA = __logf(cA.x) + __logf(cA.y);
      const float LB = __logf(cB.x) + __logf(cB.y);

      while (__hip_atomic_load(&prod, __ATOMIC_ACQUIRE, __HIP_MEMORY_SCOPE_WORKGROUP) <= off)
        __builtin_amdgcn_s_sleep(32);

      const __fp16* slot = &ring[off & 1][0][0];
#pragma unroll 1
      for (int tt = 0; tt < CH; ++tt) {
        const float hv = (float)slot[tt * HID + lane];
        const float z  = rlf(dpp_wave_sum(hv * wo), 63);
        const float pr = sigm(z + bout);
        const float Lt = (tt < 64) ? rlf(LA, tt) : rlf(LB, tt - 64);
        const float pn = (tt == 0) ? pr : pr * D;
        lsum = fmaf(pn, Lt, lsum);
        psum += pn;
        if (tt == 0)           D = S * (1.0f - pr);   // chunk t=0 undiscounted (ref quirk)
        else if (tt < CH - 1)  D *= (1.0f - pr);
        else                   S = D;                  // carry excludes (1-p_last)
      }
      if (lane == 0)
        __hip_atomic_store(&cons, off + 1, __ATOMIC_RELEASE, __HIP_MEMORY_SCOPE_WORKGROUP);
    }
    if (lane == 0) atomicAdd(out, coef * (lsum - OL * psum));
  }
}

extern "C" void kernel_launch(void* const* d_in, const int* in_sizes, int n_in,
                              void* d_out, int out_size, void* d_ws, size_t ws_size,
                              hipStream_t stream) {
  (void)hipMemsetAsync(d_out, 0, sizeof(float), stream);

  pc_lstm_kernel<<<dim3(1024), dim3(128), 0, stream>>>(
      (const int*)d_in[0],    // inds
      (const float*)d_in[1],  // p
      (const float*)d_in[2],  // ls_probs
      (const float*)d_in[3],  // open_probs
      (const int*)d_in[4],    // open_slices
      (const float*)d_in[5],  // open_hx
      (const float*)d_in[6],  // W_ih
      (const float*)d_in[7],  // W_hh
      (const float*)d_in[8],  // b_ih
      (const float*)d_in[9],  // b_hh
      (const float*)d_in[10], // W_out
      (const float*)d_in[11], // b_out
      (const int*)d_in[12],   // n_chunks
      (float*)d_out);
}